// Round 3
// baseline (680.467 us; speedup 1.0000x reference)
//
#include <hip/hip_runtime.h>
#include <stdint.h>

// UpsampleUpFIRDn: 2x upsample + 4x4 FIR (upfirdn2d, up=2, down=1, pad0=2, pad1=1)
// x: (8,64,256,256) FP32 -> out: (8,64,512,512) FP32; kernel: 4x4 FP32 (pre-scaled by factor^2)
//
// R1 post-mortem: NaN proved input memory is fp32.
// R2 post-mortem: error 4.92 > max|ref|=3.44 proved d_out is FP32 (reference output
// dtype), not bf16 — packed-bf16 stores decoded as scrambled fp32. Store fp32.
//
// Parity decomposition (verified analytically vs the flip+dilated-conv reference):
//   output row y: py=y&1, i=y>>1
//     py=0: taps (row i-1, krow 3), (row i, krow 1)
//     py=1: taps (row i,   krow 2), (row i+1, krow 0)
//   same mapping for columns. Each output = 4 FMAs, zero-padded borders.

#define IN_H 256
#define IN_W 256
#define OUT_H 512
#define OUT_W 512

__global__ __launch_bounds__(256) void upfirdn2x_kernel(
    const float* __restrict__ x,    // [nch][256][256]
    const float* __restrict__ k2,   // [4][4]
    float* __restrict__ out)        // [nch][512][512]
{
    const int t  = threadIdx.x & 63;   // 64 threads across one output row, 8 outputs each
    const int ty = threadIdx.x >> 6;   // 4 output rows per block; wave == one row (uniform branches)
    const int y  = blockIdx.x * 4 + ty;
    const int ch = blockIdx.y;

    const int py = y & 1;
    const int i  = y >> 1;

    int rA, rB, krA, krB;
    if (py == 0) { rA = i - 1; krA = 3; rB = i;     krB = 1; }
    else         { rA = i;     krA = 2; rB = i + 1; krB = 0; }
    const bool vA = (rA >= 0) && (rA < IN_H);
    const bool vB = (rB >= 0) && (rB < IN_H);
    const int rAc = vA ? rA : 0;
    const int rBc = vB ? rB : 0;

    // weights: the two tap kernel-rows, all 4 columns; zeroed if the tap row is out of range
    float wA[4], wB[4];
#pragma unroll
    for (int c = 0; c < 4; ++c) {
        wA[c] = vA ? k2[krA * 4 + c] : 0.0f;
        wB[c] = vB ? k2[krB * 4 + c] : 0.0f;
    }

    const float* xc   = x + (size_t)ch * (IN_H * IN_W);
    const float* rowA = xc + rAc * IN_W;
    const float* rowB = xc + rBc * IN_W;

    const int c0 = 4 * t;  // input cols c0..c0+3 (16B-aligned float4)
    const float4 a4 = *reinterpret_cast<const float4*>(rowA + c0);
    const float4 b4 = *reinterpret_cast<const float4*>(rowB + c0);

    // cols c0-1 .. c0+4, zero-padded at image edges
    float cA[6], cB[6];
    cA[0] = (t > 0)  ? rowA[c0 - 1] : 0.0f;
    cB[0] = (t > 0)  ? rowB[c0 - 1] : 0.0f;
    cA[5] = (t < 63) ? rowA[c0 + 4] : 0.0f;
    cB[5] = (t < 63) ? rowB[c0 + 4] : 0.0f;
    cA[1] = a4.x; cA[2] = a4.y; cA[3] = a4.z; cA[4] = a4.w;
    cB[1] = b4.x; cB[2] = b4.y; cB[3] = b4.z; cB[4] = b4.w;

    float o[8];
#pragma unroll
    for (int u = 0; u < 8; ++u) {
        const int u2 = u >> 1;
        if ((u & 1) == 0) {
            // px=0: cols (j-1, kcol 3), (j, kcol 1)
            o[u] = wA[3] * cA[u2] + wA[1] * cA[u2 + 1]
                 + wB[3] * cB[u2] + wB[1] * cB[u2 + 1];
        } else {
            // px=1: cols (j, kcol 2), (j+1, kcol 0)
            o[u] = wA[2] * cA[u2 + 1] + wA[0] * cA[u2 + 2]
                 + wB[2] * cB[u2 + 1] + wB[0] * cB[u2 + 2];
        }
    }

    float* op = out + (size_t)ch * (OUT_H * OUT_W) + (size_t)y * OUT_W + 8 * t;
    *reinterpret_cast<float4*>(op)     = make_float4(o[0], o[1], o[2], o[3]);
    *reinterpret_cast<float4*>(op + 4) = make_float4(o[4], o[5], o[6], o[7]);
}

extern "C" void kernel_launch(void* const* d_in, const int* in_sizes, int n_in,
                              void* d_out, int out_size, void* d_ws, size_t ws_size,
                              hipStream_t stream) {
    const float* x  = (const float*)d_in[0];   // fp32, 8*64*256*256
    const float* k2 = (const float*)d_in[1];   // fp32, 16 elems
    float* out = (float*)d_out;                // fp32, 8*64*512*512

    const int nch = in_sizes[0] / (IN_H * IN_W);  // 8*64 = 512
    dim3 block(256);
    dim3 grid(OUT_H / 4, nch);
    upfirdn2x_kernel<<<grid, block, 0, stream>>>(x, k2, out);
}